// Round 1
// baseline (218.360 us; speedup 1.0000x reference)
//
#include <hip/hip_runtime.h>
#include <hip/hip_bf16.h>
#include <math.h>

// Problem constants (fixed by setup_inputs)
#define CIN      8
#define H_IN     100
#define W_IN     136
#define NPIX     (H_IN * W_IN)      // 13600
#define OH       (2 * H_IN)          // 200
#define OW       (2 * W_IN)          // 272
#define ONPIX    (OH * OW)           // 54400
#define NPARAMS  169
#define EPSV     1e-5f

// param layout: w0[8][10] @0, w1[8][8] @80, w2[8] @144, b0 @152, b1 @160, b2 @168

__global__ __launch_bounds__(256, 2)
void mask_head_fused(const float* __restrict__ mask_feats,   // [N,8,100,136]
                     const float* __restrict__ params,       // [n,169]
                     const float* __restrict__ locs,         // [n,2]
                     const float* __restrict__ gt,           // [n,1,200,272]
                     const int*   __restrict__ im_inds,      // [n]
                     const int*   __restrict__ fpn_levels,   // [n]
                     float*       __restrict__ losses)       // [n]
{
    const int inst = blockIdx.x;
    const int tid  = threadIdx.x;

    __shared__ float s_par[NPARAMS];
    __shared__ float s_logit[NPIX];
    __shared__ float s_red[12];

    if (tid < NPARAMS) s_par[tid] = params[inst * NPARAMS + tid];

    const int   im  = im_inds[inst];
    const int   lvl = fpn_levels[inst];
    // SOI = {8,16,32,64,128} -> inv = exp2(-(3+lvl)), exact
    const float inv_soi = exp2f(-(float)(3 + lvl));
    const float lx = locs[inst * 2 + 0];
    const float ly = locs[inst * 2 + 1];

    __syncthreads();

    const float* feat = mask_feats + (size_t)im * (CIN * NPIX);

    // ---------------- Phase A: logits -> LDS ----------------
    #pragma unroll 1
    for (int base = 0; base < NPIX; base += 1024) {
        const int p0 = base + tid;
        float in[10][4];
        #pragma unroll
        for (int k = 0; k < 4; ++k) {
            int p  = p0 + (k << 8);
            int pc = p < NPIX ? p : NPIX - 1;
            int y  = pc / W_IN;
            int x  = pc - y * W_IN;
            in[0][k] = (lx - (float)(x * 8 + 4)) * inv_soi;
            in[1][k] = (ly - (float)(y * 8 + 4)) * inv_soi;
            #pragma unroll
            for (int c = 0; c < CIN; ++c)
                in[2 + c][k] = feat[c * NPIX + pc];
        }

        // layer 0: 10 -> 8, relu
        float h0[8][4];
        #pragma unroll
        for (int o = 0; o < 8; ++o) {
            float b = s_par[152 + o];
            float a0 = b, a1 = b, a2 = b, a3 = b;
            #pragma unroll
            for (int i = 0; i < 10; ++i) {
                float w = s_par[o * 10 + i];
                a0 = fmaf(w, in[i][0], a0);
                a1 = fmaf(w, in[i][1], a1);
                a2 = fmaf(w, in[i][2], a2);
                a3 = fmaf(w, in[i][3], a3);
            }
            h0[o][0] = fmaxf(a0, 0.f);
            h0[o][1] = fmaxf(a1, 0.f);
            h0[o][2] = fmaxf(a2, 0.f);
            h0[o][3] = fmaxf(a3, 0.f);
        }

        // layer 1: 8 -> 8, relu
        float h1[8][4];
        #pragma unroll
        for (int o = 0; o < 8; ++o) {
            float b = s_par[160 + o];
            float a0 = b, a1 = b, a2 = b, a3 = b;
            #pragma unroll
            for (int i = 0; i < 8; ++i) {
                float w = s_par[80 + o * 8 + i];
                a0 = fmaf(w, h0[i][0], a0);
                a1 = fmaf(w, h0[i][1], a1);
                a2 = fmaf(w, h0[i][2], a2);
                a3 = fmaf(w, h0[i][3], a3);
            }
            h1[o][0] = fmaxf(a0, 0.f);
            h1[o][1] = fmaxf(a1, 0.f);
            h1[o][2] = fmaxf(a2, 0.f);
            h1[o][3] = fmaxf(a3, 0.f);
        }

        // layer 2: 8 -> 1
        float b2 = s_par[168];
        float o0 = b2, o1 = b2, o2 = b2, o3 = b2;
        #pragma unroll
        for (int i = 0; i < 8; ++i) {
            float w = s_par[144 + i];
            o0 = fmaf(w, h1[i][0], o0);
            o1 = fmaf(w, h1[i][1], o1);
            o2 = fmaf(w, h1[i][2], o2);
            o3 = fmaf(w, h1[i][3], o3);
        }
        float outv[4] = {o0, o1, o2, o3};
        #pragma unroll
        for (int k = 0; k < 4; ++k) {
            int p = p0 + (k << 8);
            if (p < NPIX) s_logit[p] = outv[k];
        }
    }

    __syncthreads();

    // ---------------- Phase B: upsample x2 + sigmoid + dice sums ----------------
    // aligned_bilinear(f=2): out[oy][ox] = bilerp at src ((max(oy-1,0))/2, (max(ox-1,0))/2)
    // with right/bottom edge clamp (pad) at 99/135.
    float inter = 0.f, ssum = 0.f, tsum = 0.f;
    const float* gtp = gt + (size_t)inst * ONPIX;

    #pragma unroll 1
    for (int base = 0; base < ONPIX; base += 1024) {
        const int p = base + (tid << 2);
        if (p < ONPIX) {
            const float4 t4 = *(const float4*)(gtp + p);
            const float tv[4] = {t4.x, t4.y, t4.z, t4.w};
            const int oy  = p / OW;            // 272 | p%4==0 -> row-uniform per thread
            const int ox0 = p - oy * OW;
            const int sy  = oy > 0 ? oy - 1 : 0;
            const int y0  = sy >> 1;
            const float wy = (sy & 1) ? 0.5f : 0.f;
            const int y1  = (y0 + 1 < H_IN) ? y0 + 1 : H_IN - 1;
            const float* r0 = s_logit + y0 * W_IN;
            const float* r1 = s_logit + y1 * W_IN;
            #pragma unroll
            for (int j = 0; j < 4; ++j) {
                int ox = ox0 + j;
                int sx = ox > 0 ? ox - 1 : 0;
                int x0 = sx >> 1;
                float wx = (sx & 1) ? 0.5f : 0.f;
                int x1 = (x0 + 1 < W_IN) ? x0 + 1 : W_IN - 1;
                float a  = r0[x0], b = r0[x1];
                float c  = r1[x0], d = r1[x1];
                float top = a + wx * (b - a);
                float bot = c + wx * (d - c);
                float l   = top + wy * (bot - top);
                float s   = 1.f / (1.f + __expf(-l));
                float t   = tv[j];
                inter = fmaf(s, t, inter);
                ssum  = fmaf(s, s, ssum);
                tsum  = fmaf(t, t, tsum);
            }
        }
    }

    // block reduction (4 waves of 64)
    #pragma unroll
    for (int off = 32; off > 0; off >>= 1) {
        inter += __shfl_down(inter, off, 64);
        ssum  += __shfl_down(ssum,  off, 64);
        tsum  += __shfl_down(tsum,  off, 64);
    }
    const int wid = tid >> 6;
    if ((tid & 63) == 0) {
        s_red[wid * 3 + 0] = inter;
        s_red[wid * 3 + 1] = ssum;
        s_red[wid * 3 + 2] = tsum;
    }
    __syncthreads();
    if (tid == 0) {
        float I = 0.f, S = 0.f, T = 0.f;
        #pragma unroll
        for (int w = 0; w < 4; ++w) {
            I += s_red[w * 3 + 0];
            S += s_red[w * 3 + 1];
            T += s_red[w * 3 + 2];
        }
        float uni = S + T + EPSV;
        losses[inst] = 1.f - 2.f * I / uni;
    }
}

__global__ __launch_bounds__(512)
void loss_mean_kernel(const float* __restrict__ losses, float* __restrict__ out, int n)
{
    __shared__ float s_red[8];
    float v = 0.f;
    for (int i = threadIdx.x; i < n; i += 512) v += losses[i];
    #pragma unroll
    for (int off = 32; off > 0; off >>= 1) v += __shfl_down(v, off, 64);
    const int wid = threadIdx.x >> 6;
    if ((threadIdx.x & 63) == 0) s_red[wid] = v;
    __syncthreads();
    if (threadIdx.x == 0) {
        float s = 0.f;
        #pragma unroll
        for (int w = 0; w < 8; ++w) s += s_red[w];
        out[0] = s / (float)n;
    }
}

extern "C" void kernel_launch(void* const* d_in, const int* in_sizes, int n_in,
                              void* d_out, int out_size, void* d_ws, size_t ws_size,
                              hipStream_t stream)
{
    const float* mask_feats = (const float*)d_in[0];
    const float* params     = (const float*)d_in[1];
    const float* locs       = (const float*)d_in[2];
    const float* gt         = (const float*)d_in[3];
    const int*   im_inds    = (const int*)d_in[4];
    const int*   fpn_levels = (const int*)d_in[5];
    // d_in[6] = mask_feat_stride (always 8 for this problem)

    const int n = in_sizes[4];          // 500 instances
    float* losses = (float*)d_ws;       // n floats of scratch

    mask_head_fused<<<n, 256, 0, stream>>>(mask_feats, params, locs, gt,
                                           im_inds, fpn_levels, losses);
    loss_mean_kernel<<<1, 512, 0, stream>>>(losses, (float*)d_out, n);
}